// Round 2
// baseline (265.498 us; speedup 1.0000x reference)
//
#include <hip/hip_runtime.h>
#include <hip/hip_bf16.h>

typedef __attribute__((ext_vector_type(8))) short short8;
typedef __attribute__((ext_vector_type(4))) float f32x4;
typedef __attribute__((ext_vector_type(4))) unsigned int u32x4;
typedef __attribute__((ext_vector_type(2))) unsigned int u32x2;

#define DIN  4096
#define DOUT 4096
#define NTOK 16384

static __device__ __forceinline__ unsigned short f2b(float f) {
  union { __hip_bfloat16 h; unsigned short u; } cv;
  cv.h = __float2bfloat16(f);
  return cv.u;
}

// ---------------- prologue: transpose+convert weights to bf16 ----------------
// btt_r[n][b][k] f32 -> Rt[n][c=k][b] bf16
__global__ __launch_bounds__(256) void prep_r(const float* __restrict__ r,
                                              unsigned short* __restrict__ rt) {
  __shared__ unsigned short tile[64 * 132];   // [b][k], padded stride 132 (264B)
  const int n = blockIdx.x;
  const int q = threadIdx.x;
#pragma unroll
  for (int it = 0; it < 8; ++it) {
    const int idx = q + it * 256;             // float4 units, 2048 total
    const int b = idx >> 5, k4 = idx & 31;
    const float4 v = *(const float4*)(r + (size_t)n * 8192 + b * 128 + k4 * 4);
    unsigned int lo = (unsigned)f2b(v.x) | ((unsigned)f2b(v.y) << 16);
    unsigned int hi = (unsigned)f2b(v.z) | ((unsigned)f2b(v.w) << 16);
    u32x2 pk = {lo, hi};
    *(u32x2*)((char*)tile + (b * 264 + k4 * 8)) = pk;
  }
  __syncthreads();
#pragma unroll
  for (int it = 0; it < 32; ++it) {
    const int o = q + it * 256;               // o = c*64 + b
    const int c = o >> 6, b = o & 63;
    rt[(size_t)n * 8192 + o] = tile[b * 132 + c];
  }
}

// btt_l[m][j][a] f32 -> Lt[m][a][j] bf16
__global__ __launch_bounds__(256) void prep_l(const float* __restrict__ l,
                                              unsigned short* __restrict__ lt) {
  __shared__ unsigned short tile[128 * 68];   // [j][a], padded stride 68 (136B)
  const int m = blockIdx.x;
  const int q = threadIdx.x;
#pragma unroll
  for (int it = 0; it < 8; ++it) {
    const int idx = q + it * 256;             // float4 units, 2048 total
    const int j = idx >> 4, a4 = idx & 15;
    const float4 v = *(const float4*)(l + (size_t)m * 8192 + j * 64 + a4 * 4);
    unsigned int lo = (unsigned)f2b(v.x) | ((unsigned)f2b(v.y) << 16);
    unsigned int hi = (unsigned)f2b(v.z) | ((unsigned)f2b(v.w) << 16);
    u32x2 pk = {lo, hi};
    *(u32x2*)((char*)tile + (j * 136 + a4 * 8)) = pk;
  }
  __syncthreads();
#pragma unroll
  for (int it = 0; it < 32; ++it) {
    const int o = q + it * 256;               // o = a*128 + j
    const int a = o >> 7, j = o & 127;
    lt[(size_t)m * 8192 + o] = tile[j * 68 + a];
  }
}

// ---------------- kernel1: stage1  h[t,n,c] = sum_b x[t,n*64+b]*R[n][b][c] ----
// h layout (chunk-local): [t>>4][n][c][t&15] bf16
__global__ __launch_bounds__(512) void k1(const float* __restrict__ x,
                                          const unsigned short* __restrict__ rt,
                                          unsigned short* __restrict__ hbuf,
                                          int tok0) {
  __shared__ unsigned short xs[32 * 64];      // x tile, swizzled rows of 128B
  __shared__ unsigned short rs[128 * 64];     // Rt tile, swizzled rows of 128B
  const int bid = blockIdx.x;
  const int tb = bid >> 2, ns = bid & 3;
  const int tid = threadIdx.x;
  const int wave = tid >> 6, lane = tid & 63;
  const int l15 = lane & 15, l4 = lane >> 4;
  const int t0 = tok0 + tb * 32;

  const int xr = tid >> 4, xc4 = tid & 15;
  const int xbyte = xr * 128 + ((xc4 * 8) ^ ((xr & 7) << 4));
  const int sw = (l15 & 7) << 4;
  const int ccol = wave * 16 + l15;

  for (int ni = 0; ni < 16; ++ni) {
    const int n = ns * 16 + ni;
    __syncthreads();
    // stage x_n tile (32x64 f32 -> bf16, swizzled)
    {
      const float4 v = *(const float4*)(x + (size_t)(t0 + xr) * DIN + n * 64 + xc4 * 4);
      unsigned int lo = (unsigned)f2b(v.x) | ((unsigned)f2b(v.y) << 16);
      unsigned int hi = (unsigned)f2b(v.z) | ((unsigned)f2b(v.w) << 16);
      u32x2 pk = {lo, hi};
      *(u32x2*)((char*)xs + xbyte) = pk;
    }
    // stage Rt_n tile (128 rows x 64 bf16 = 1024 x16B vectors, 2 per thread)
#pragma unroll
    for (int it = 0; it < 2; ++it) {
      const int q = tid + it * 512;
      const int rr = q >> 3, rsl = q & 7;
      u32x4 v = *(const u32x4*)(rt + (size_t)n * 8192 + rr * 64 + rsl * 8);
      *(u32x4*)((char*)rs + (rr * 128 + ((rsl * 16) ^ ((rr & 7) << 4)))) = v;
    }
    __syncthreads();

    f32x4 acc0 = {0.f, 0.f, 0.f, 0.f};
    f32x4 acc1 = {0.f, 0.f, 0.f, 0.f};
#pragma unroll
    for (int ks = 0; ks < 2; ++ks) {
      const int kb = ks * 64 + l4 * 16;
      short8 a0 = *(const short8*)((char*)xs + ((l15) * 128 + (kb ^ sw)));
      short8 a1 = *(const short8*)((char*)xs + ((16 + l15) * 128 + (kb ^ sw)));
      short8 bv = *(const short8*)((char*)rs + (ccol * 128 + (kb ^ ((ccol & 7) << 4))));
      acc0 = __builtin_amdgcn_mfma_f32_16x16x32_bf16(a0, bv, acc0, 0, 0, 0);
      acc1 = __builtin_amdgcn_mfma_f32_16x16x32_bf16(a1, bv, acc1, 0, 0, 0);
    }
    // write h: D row (token-in-group) = (lane>>4)*4 + reg, col = ccol
    const int tii0 = l4 * 4;
#pragma unroll
    for (int mt = 0; mt < 2; ++mt) {
      const f32x4 a = mt ? acc1 : acc0;
      unsigned int lo = (unsigned)f2b(a[0]) | ((unsigned)f2b(a[1]) << 16);
      unsigned int hi = (unsigned)f2b(a[2]) | ((unsigned)f2b(a[3]) << 16);
      u32x2 pk = {lo, hi};
      const int tioG = tb * 2 + mt;           // chunk-local 16-token group
      unsigned short* dst = hbuf + (((size_t)(tioG * 64 + n) * 128 + ccol) * 16 + tii0);
      *(u32x2*)dst = pk;
    }
  }
}

// ---------------- kernel2: stage2  y[t,m*64+a] = sum_j h'[t,m,j]*L[m][j][a] + bias
// h'[t][m][j=n*2+r] = h[t][n][m*2+r]
__global__ __launch_bounds__(512) void k2(const unsigned short* __restrict__ hbuf,
                                          const unsigned short* __restrict__ lt,
                                          const float* __restrict__ bias,
                                          float* __restrict__ y,
                                          int tok0) {
  __shared__ unsigned short as_[32 * 128];    // h' tile [t][j], swizzled rows 256B
  __shared__ unsigned short ls[64 * 128];     // Lt tile [a][j], swizzled rows 256B
  const int bid = blockIdx.x;
  const int tb = bid >> 2, ms = bid & 3;
  const int tid = threadIdx.x;
  const int wave = tid >> 6, lane = tid & 63;
  const int l15 = lane & 15, l4 = lane >> 4;
  const int wr = wave >> 2, wc = wave & 3;

  const int hh = tid & 1, nr = (tid >> 1) & 127, tio_l = tid >> 8;
  const int nn = nr >> 1, r2 = nr & 1;

  const int ta = wr * 16 + l15;
  const int aa = wc * 16 + l15;
  const int swt = (ta & 7) << 4;
  const int swa = (aa & 7) << 4;

  for (int mi = 0; mi < 16; ++mi) {
    const int m = ms * 16 + mi;
    __syncthreads();
    // stage A (gather h' columns for this m, transpose through LDS)
    {
      const unsigned short* src =
          hbuf + (((size_t)((tb * 2 + tio_l) * 64 + nn) * 128 + (m * 2 + r2)) * 16 + hh * 8);
      u32x4 v = *(const u32x4*)src;
#pragma unroll
      for (int e = 0; e < 8; ++e) {
        const unsigned int wrd = v[e >> 1];
        const unsigned short val = (e & 1) ? (unsigned short)(wrd >> 16)
                                           : (unsigned short)(wrd & 0xffff);
        const int t = tio_l * 16 + hh * 8 + e;
        *(unsigned short*)((char*)as_ + (t * 256 + ((nr * 2) ^ ((t & 7) << 4)))) = val;
      }
    }
    // stage Lt_m (64 rows x 128 bf16 = 1024 x16B vectors, 2 per thread)
#pragma unroll
    for (int it = 0; it < 2; ++it) {
      const int q2 = tid + it * 512;
      const int ar = q2 >> 4, sl = q2 & 15;
      u32x4 v = *(const u32x4*)(lt + (size_t)m * 8192 + ar * 128 + sl * 8);
      *(u32x4*)((char*)ls + (ar * 256 + ((sl * 16) ^ ((ar & 7) << 4)))) = v;
    }
    __syncthreads();

    f32x4 acc = {0.f, 0.f, 0.f, 0.f};
#pragma unroll
    for (int ks = 0; ks < 4; ++ks) {
      const int kb = ks * 64 + l4 * 16;
      short8 av = *(const short8*)((char*)as_ + (ta * 256 + (kb ^ swt)));
      short8 bv = *(const short8*)((char*)ls + (aa * 256 + (kb ^ swa)));
      acc = __builtin_amdgcn_mfma_f32_16x16x32_bf16(av, bv, acc, 0, 0, 0);
    }
    const float bvv = bias[m * 64 + aa];
    const int tg0 = tok0 + tb * 32 + wr * 16 + l4 * 4;
#pragma unroll
    for (int jj = 0; jj < 4; ++jj) {
      y[(size_t)(tg0 + jj) * DOUT + m * 64 + aa] = acc[jj] + bvv;
    }
  }
}

extern "C" void kernel_launch(void* const* d_in, const int* in_sizes, int n_in,
                              void* d_out, int out_size, void* d_ws, size_t ws_size,
                              hipStream_t stream) {
  const float* x    = (const float*)d_in[0];
  const float* bl   = (const float*)d_in[1];
  const float* br   = (const float*)d_in[2];
  const float* bias = (const float*)d_in[3];
  float* y = (float*)d_out;

  unsigned short* rt   = (unsigned short*)d_ws;          // 1 MB
  unsigned short* ltw  = rt + 64 * 8192;                 // 1 MB
  unsigned short* hbuf = ltw + 64 * 8192;                // chunk*8192*2 B

  // pick largest chunk whose h buffer fits the workspace (L3 residency target)
  size_t fixed = (size_t)2 * 64 * 8192 * 2;
  int chunk = 4096;
  while (chunk > 512 && fixed + (size_t)chunk * 8192 * 2 > ws_size) chunk >>= 1;
  const int nchunk = NTOK / chunk;
  const int grid = (chunk / 32) * 4;

  prep_r<<<64, 256, 0, stream>>>(br, rt);
  prep_l<<<64, 256, 0, stream>>>(bl, ltw);
  for (int c = 0; c < nchunk; ++c) {
    k1<<<grid, 512, 0, stream>>>(x, rt, hbuf, c * chunk);
    k2<<<grid, 512, 0, stream>>>(hbuf, ltw, bias, y, c * chunk);
  }
}